// Round 1
// baseline (472.479 us; speedup 1.0000x reference)
//
#include <hip/hip_runtime.h>
#include <math.h>

#define NWAVE 8           // waves per block; 1 wave == 1 batch element
#define ZSTR  260         // padded LDS row stride (floats): 8 node-rows hit distinct banks
#define EPSLN 1e-5f

struct KP {
  const float* Z[8];
  const float* A;
  const float* W0; const float* b0; const float* g0; const float* be0; const float* Wg0; const float* bg0;
  const float* W1; const float* b1; const float* g1; const float* be1; const float* Wg1; const float* bg1; const float* WgT1;
  const float* W2; const float* b2; const float* g2; const float* be2; const float* Wg2; const float* bg2; const float* WgT2;
  const float* Wout; const float* bout;
  float* out;
  int useT;
};

// Transpose Wg[i][f][o] (f=7*D, o=7) -> WgTI[c][i][o][4] where f = 4c+j.
// Lane (i,o) reading chunk c then hits a contiguous float4; 56 active lanes read
// one contiguous 896B block per chunk step.
__global__ void transpose_wg(const float* __restrict__ src, float* __restrict__ dst, int D) {
  const int F = 7 * D;
  const int total = 8 * F * 7;
  int t = blockIdx.x * 256 + threadIdx.x;
  if (t >= total) return;
  const int o  = t % 7;
  const int fi = t / 7;
  const int f  = fi % F;
  const int i  = fi / F;
  dst[(((f >> 2) * 8 + i) * 7 + o) * 4 + (f & 3)] = src[t];
}

template<int D, int O>
__device__ __forceinline__ void layer_fwd(
    float* zb, float* wb, const float* gbf, int u,
    const float* __restrict__ W, const float* __restrict__ bias,
    const float* __restrict__ gsc, const float* __restrict__ bsh,
    const float* __restrict__ Wg, const float* __restrict__ bg,
    const float* __restrict__ WgT, bool useT)
{
  const int gi = u >> 3, o8 = u & 7;

  // ---------- gate logits: logit[o] = bg + sum_k sum_d Z[n_k][d] * Wg[i][k*D+d][o]
  float acc = -3.0e38f;
  if (o8 < 7) {
    acc = bg[gi * 7 + o8];
    for (int k = 0; k < 7; ++k) {
      const int nk = k + (k >= gi);
      const float* zn = zb + nk * ZSTR;
      if constexpr (D == 3) {
        const float* wp = Wg + (gi * 21 + k * 3) * 7 + o8;
        acc += zn[0] * wp[0] + zn[1] * wp[7] + zn[2] * wp[14];
      } else {
        if (useT) {
          const float* wp = WgT + (gi * 7 + o8) * 4 + (k * (D / 4)) * 224;
          #pragma unroll 4
          for (int d = 0; d < D; d += 4, wp += 224) {
            const float4 z4 = *(const float4*)(zn + d);
            const float4 w4 = *(const float4*)wp;
            acc += z4.x * w4.x + z4.y * w4.y + z4.z * w4.z + z4.w * w4.w;
          }
        } else {
          const float* wp = Wg + (gi * 7 * D + k * D) * 7 + o8;
          #pragma unroll 4
          for (int d = 0; d < D; d += 4) {
            const float4 z4 = *(const float4*)(zn + d);
            acc += z4.x * wp[(d + 0) * 7] + z4.y * wp[(d + 1) * 7]
                 + z4.z * wp[(d + 2) * 7] + z4.w * wp[(d + 3) * 7];
          }
        }
      }
    }
  }
  // softmax over the 8-lane group (lane o8==7 contributes -inf / 0)
  float m = acc;
  #pragma unroll
  for (int mk = 4; mk; mk >>= 1) m = fmaxf(m, __shfl_xor(m, mk, 8));
  float e = (o8 < 7) ? __expf(acc - m) : 0.0f;
  float ssum = e;
  #pragma unroll
  for (int mk = 4; mk; mk >>= 1) ssum += __shfl_xor(ssum, mk, 8);
  if (o8 < 7) wb[gi * 8 + o8] = (e / ssum) * gbf[gi * 8 + o8];
  __syncthreads();

  // ---------- x = Z + NZ (into regs, then write back over Z)
  if constexpr (D == 3) {
    const int i3 = u / 3, d3 = u - i3 * 3;  // valid for u<24
    float x = 0.f;
    if (u < 24) {
      x = zb[i3 * ZSTR + d3];
      #pragma unroll
      for (int k = 0; k < 7; ++k) {
        const int nk = k + (k >= i3);
        x += wb[i3 * 8 + k] * zb[nk * ZSTR + d3];
      }
    }
    __syncthreads();
    if (u < 24) zb[i3 * ZSTR + d3] = x;
    __syncthreads();
  } else {
    constexpr int IPG = 256 / D;   // nodes covered per wave pass (1 or 2)
    constexpr int NIT = 8 / IPG;
    const int s = u * 4;
    const int ioff = s / D;
    const int dd = s - ioff * D;
    float4 xr[NIT];
    #pragma unroll
    for (int it = 0; it < NIT; ++it) {
      const int i = it * IPG + ioff;
      float wk[7];
      #pragma unroll
      for (int k = 0; k < 7; ++k) wk[k] = wb[i * 8 + k];
      float4 x = *(const float4*)(zb + i * ZSTR + dd);
      #pragma unroll
      for (int k = 0; k < 7; ++k) {
        const int nk = k + (k >= i);
        const float4 z4 = *(const float4*)(zb + nk * ZSTR + dd);
        x.x += wk[k] * z4.x; x.y += wk[k] * z4.y;
        x.z += wk[k] * z4.z; x.w += wk[k] * z4.w;
      }
      xr[it] = x;
    }
    __syncthreads();
    #pragma unroll
    for (int it = 0; it < NIT; ++it) {
      const int i = it * IPG + ioff;
      *(float4*)(zb + i * ZSTR + dd) = xr[it];
    }
    __syncthreads();
  }

  // ---------- h = x @ W + b ; LayerNorm ; relu ; write back as next Z
  {
    constexpr int IPG = 256 / O;   // 1, 2 or 4 nodes per wave pass
    const int s = u * 4;
    const int ioff = s / O;
    const int oo = s - ioff * O;
    for (int ib = 0; ib < 8; ib += IPG) {
      const int i = ib + ioff;
      float4 acc4 = *(const float4*)(bias + i * O + oo);
      const float* wrow = W + i * D * O + oo;
      if constexpr (D == 3) {
        #pragma unroll
        for (int d = 0; d < 3; ++d) {
          const float xs = zb[i * ZSTR + d];
          const float4 w4 = *(const float4*)(wrow + d * O);
          acc4.x += xs * w4.x; acc4.y += xs * w4.y;
          acc4.z += xs * w4.z; acc4.w += xs * w4.w;
        }
      } else {
        #pragma unroll 4
        for (int d = 0; d < D; d += 4) {
          const float4 x4 = *(const float4*)(zb + i * ZSTR + d);
          const float4 w0 = *(const float4*)(wrow + (d + 0) * O);
          const float4 w1 = *(const float4*)(wrow + (d + 1) * O);
          const float4 w2 = *(const float4*)(wrow + (d + 2) * O);
          const float4 w3 = *(const float4*)(wrow + (d + 3) * O);
          acc4.x += x4.x * w0.x + x4.y * w1.x + x4.z * w2.x + x4.w * w3.x;
          acc4.y += x4.x * w0.y + x4.y * w1.y + x4.z * w2.y + x4.w * w3.y;
          acc4.z += x4.x * w0.z + x4.y * w1.z + x4.z * w2.z + x4.w * w3.z;
          acc4.w += x4.x * w0.w + x4.y * w1.w + x4.z * w2.w + x4.w * w3.w;
        }
      }
      // LayerNorm across the O outputs of node i (spread over GS lanes)
      constexpr int GS = O / 4;
      float s1 = acc4.x + acc4.y + acc4.z + acc4.w;
      float s2 = acc4.x * acc4.x + acc4.y * acc4.y + acc4.z * acc4.z + acc4.w * acc4.w;
      #pragma unroll
      for (int mk = GS >> 1; mk; mk >>= 1) {
        s1 += __shfl_xor(s1, mk, GS);
        s2 += __shfl_xor(s2, mk, GS);
      }
      const float mean = s1 * (1.0f / O);
      const float var  = s2 * (1.0f / O) - mean * mean;
      const float rs   = rsqrtf(var + EPSLN);
      const float4 gg = *(const float4*)(gsc + i * O + oo);
      const float4 bb = *(const float4*)(bsh + i * O + oo);
      float4 r;
      r.x = fmaxf((acc4.x - mean) * rs * gg.x + bb.x, 0.f);
      r.y = fmaxf((acc4.y - mean) * rs * gg.y + bb.y, 0.f);
      r.z = fmaxf((acc4.z - mean) * rs * gg.z + bb.z, 0.f);
      r.w = fmaxf((acc4.w - mean) * rs * gg.w + bb.w, 0.f);
      *(float4*)(zb + i * ZSTR + oo) = r;
    }
  }
  __syncthreads();
}

__launch_bounds__(512, 4)
__global__ void actor_fused(KP p)
{
  __shared__ float zA[NWAVE * 8 * ZSTR];
  __shared__ float wbuf[NWAVE * 64];
  __shared__ float gbuf[NWAVE * 64];
  const int wave = threadIdx.x >> 6;
  const int u = threadIdx.x & 63;
  const int gb = blockIdx.x * NWAVE + wave;   // batch element of this wave
  float* zb  = zA   + wave * (8 * ZSTR);
  float* wb  = wbuf + wave * 64;
  float* gbf = gbuf + wave * 64;

  // gates: gbuf[i][k] = A[b, gidx(i,k)]
  {
    const int i = u >> 3, o8 = u & 7;
    if (o8 < 7) {
      const int j = o8 + (o8 >= i);
      const int gidx = (i == 0 && j <= 3) ? j : 8 * j + i;
      gbf[i * 8 + o8] = p.A[gb * 64 + gidx];
    }
  }
  // initial Z (8 nodes x 3)
  if (u < 3) {
    #pragma unroll
    for (int i = 0; i < 8; ++i) zb[i * ZSTR + u] = p.Z[i][gb * 3 + u];
  }
  __syncthreads();

  layer_fwd<3, 256>(zb, wb, gbf, u, p.W0, p.b0, p.g0, p.be0, p.Wg0, p.bg0, nullptr, false);
  layer_fwd<256, 128>(zb, wb, gbf, u, p.W1, p.b1, p.g1, p.be1, p.Wg1, p.bg1, p.WgT1, p.useT != 0);
  layer_fwd<128, 64>(zb, wb, gbf, u, p.W2, p.b2, p.g2, p.be2, p.Wg2, p.bg2, p.WgT2, p.useT != 0);

  // output projection 64 -> 5, tanh
  {
    const int i = u >> 3, o8 = u & 7;
    if (o8 < 5) {
      float acc = p.bout[i * 5 + o8];
      const float* wp = p.Wout + i * 64 * 5 + o8;
      #pragma unroll 8
      for (int d = 0; d < 64; ++d) acc += zb[i * ZSTR + d] * wp[d * 5];
      p.out[(size_t)(gb * 8 + i) * 5 + o8] = tanhf(acc);
    }
  }
}

extern "C" void kernel_launch(void* const* d_in, const int* in_sizes, int n_in,
                              void* d_out, int out_size, void* d_ws, size_t ws_size,
                              hipStream_t stream) {
  KP p;
  for (int i = 0; i < 8; ++i) p.Z[i] = (const float*)d_in[1 + i];
  p.A   = (const float*)d_in[9];
  p.W0  = (const float*)d_in[10]; p.b0 = (const float*)d_in[11];
  p.g0  = (const float*)d_in[12]; p.be0 = (const float*)d_in[13];
  p.Wg0 = (const float*)d_in[14]; p.bg0 = (const float*)d_in[15];
  p.W1  = (const float*)d_in[16]; p.b1 = (const float*)d_in[17];
  p.g1  = (const float*)d_in[18]; p.be1 = (const float*)d_in[19];
  p.Wg1 = (const float*)d_in[20]; p.bg1 = (const float*)d_in[21];
  p.W2  = (const float*)d_in[22]; p.b2 = (const float*)d_in[23];
  p.g2  = (const float*)d_in[24]; p.be2 = (const float*)d_in[25];
  p.Wg2 = (const float*)d_in[26]; p.bg2 = (const float*)d_in[27];
  p.Wout = (const float*)d_in[28]; p.bout = (const float*)d_in[29];
  p.out = (float*)d_out;

  const size_t t1_elems = 8 * 1792 * 7;  // 100352
  const size_t t2_elems = 8 * 896 * 7;   // 50176
  float* wsf = (float*)d_ws;
  const bool useT = ws_size >= (t1_elems + t2_elems) * sizeof(float);
  p.WgT1 = wsf;
  p.WgT2 = wsf + t1_elems;
  p.useT = useT ? 1 : 0;

  if (useT) {
    hipLaunchKernelGGL(transpose_wg, dim3((unsigned)((t1_elems + 255) / 256)), dim3(256), 0, stream,
                       p.Wg1, wsf, 256);
    hipLaunchKernelGGL(transpose_wg, dim3((unsigned)((t2_elems + 255) / 256)), dim3(256), 0, stream,
                       p.Wg2, wsf + t1_elems, 128);
  }
  hipLaunchKernelGGL(actor_fused, dim3(8192 / NWAVE), dim3(512), 0, stream, p);
}

// Round 2
// 294.570 us; speedup vs baseline: 1.6040x; 1.6040x over previous
//
#include <hip/hip_runtime.h>
#include <math.h>

#define NWAVE 8            // waves per block; block processes 8 batch elements
#define ZSTR  260          // per-node LDS row stride (floats)
#define SLICE (8*ZSTR+4)   // per-batch-element LDS slice stride (2084): +4 spreads banks across b
#define WSTR  68           // wbuf/gbuf per-batch stride (68%32=4 -> bank spread)
#define EPSLN 1e-5f

struct KP {
  const float* Z[8];
  const float* A;
  const float* W0; const float* b0; const float* g0; const float* be0; const float* Wg0; const float* bg0;
  const float* W1; const float* b1; const float* g1; const float* be1; const float* Wg1; const float* bg1; const float* WgT1;
  const float* W2; const float* b2; const float* g2; const float* be2; const float* Wg2; const float* bg2; const float* WgT2;
  const float* Wout; const float* bout;
  float* out;
  int useT;
};

// Transpose Wg[i][f][o] (f=7*D, o=7) -> WgT[c][i][o][4] where f = 4c+j.
__global__ void transpose_wg(const float* __restrict__ src, float* __restrict__ dst, int D) {
  const int F = 7 * D;
  const int total = 8 * F * 7;
  int t = blockIdx.x * 256 + threadIdx.x;
  if (t >= total) return;
  const int o  = t % 7;
  const int fi = t / 7;
  const int f  = fi % F;
  const int i  = fi / F;
  dst[(((f >> 2) * 8 + i) * 7 + o) * 4 + (f & 3)] = src[t];
}

// z(b, node, d) accessor base: zAll + b*SLICE + node*ZSTR
template<int D, int O>
__device__ __forceinline__ void layer_fwd(
    float* __restrict__ zAll, float* __restrict__ wAll, const float* __restrict__ gAll,
    int wave, int u,
    const float* __restrict__ W, const float* __restrict__ bias,
    const float* __restrict__ gsc, const float* __restrict__ bsh,
    const float* __restrict__ Wg, const float* __restrict__ bg,
    const float* __restrict__ WgT, bool useT)
{
  // ======== PHASE G: gate logits + softmax.  wave = node i; lane = (b, o8)
  {
    const int i = wave;
    const int b = u >> 3, o8 = u & 7;
    float acc = -3.0e38f;
    if (o8 < 7) {
      acc = bg[i * 7 + o8];
      const float* zbB = zAll + b * SLICE;
      #pragma unroll
      for (int k = 0; k < 7; ++k) {
        const int nk = k + (k >= i);
        const float* zn = zbB + nk * ZSTR;
        if constexpr (D == 3) {
          const float* wp = Wg + (i * 21 + k * 3) * 7 + o8;
          acc += zn[0] * wp[0] + zn[1] * wp[7] + zn[2] * wp[14];
        } else {
          if (useT) {
            // WgT[c][i][o][4], c = k*(D/4) + d/4 ; index = c*224 + i*28 + o*4
            const float* wp = WgT + (size_t)(k * (D / 4)) * 224 + i * 28 + o8 * 4;
            #pragma unroll 4
            for (int d = 0; d < D; d += 4, wp += 224) {
              const float4 z4 = *(const float4*)(zn + d);
              const float4 w4 = *(const float4*)wp;
              acc += z4.x * w4.x + z4.y * w4.y + z4.z * w4.z + z4.w * w4.w;
            }
          } else {
            const float* wp = Wg + (size_t)(i * 7 * D + k * D) * 7 + o8;
            for (int d = 0; d < D; ++d) acc += zn[d] * wp[d * 7];
          }
        }
      }
    }
    // softmax over the 8-lane group (lane o8==7 contributes -inf / 0)
    float m = acc;
    #pragma unroll
    for (int mk = 4; mk; mk >>= 1) m = fmaxf(m, __shfl_xor(m, mk, 8));
    float e = (o8 < 7) ? __expf(acc - m) : 0.0f;
    float ssum = e;
    #pragma unroll
    for (int mk = 4; mk; mk >>= 1) ssum += __shfl_xor(ssum, mk, 8);
    if (o8 < 7) wAll[b * WSTR + i * 8 + o8] = (e / ssum) * gAll[b * WSTR + i * 8 + o8];
  }
  __syncthreads();

  // ======== PHASE NZ: x = Z + sum_k w[k]*Z[nk].  wave = batch element (own slice only)
  {
    float* zb = zAll + wave * SLICE;
    const float* wb = wAll + wave * WSTR;
    if constexpr (D == 3) {
      const int i3 = u / 3, d3 = u - i3 * 3;
      float x = 0.f;
      if (u < 24) {
        x = zb[i3 * ZSTR + d3];
        #pragma unroll
        for (int k = 0; k < 7; ++k) {
          const int nk = k + (k >= i3);
          x += wb[i3 * 8 + k] * zb[nk * ZSTR + d3];
        }
      }
      // reads fully staged in regs before write; own slice only -> no barrier needed
      if (u < 24) zb[i3 * ZSTR + d3] = x;
    } else {
      constexpr int IPG = 256 / D;   // nodes covered per pass (1 or 2)
      constexpr int NIT = 8 / IPG;
      const int s = u * 4;
      const int ioff = s / D;
      const int dd = s - ioff * D;
      float4 xr[NIT];
      #pragma unroll
      for (int it = 0; it < NIT; ++it) {
        const int i = it * IPG + ioff;
        float wk[7];
        #pragma unroll
        for (int k = 0; k < 7; ++k) wk[k] = wb[i * 8 + k];
        float4 x = *(const float4*)(zb + i * ZSTR + dd);
        #pragma unroll
        for (int k = 0; k < 7; ++k) {
          const int nk = k + (k >= i);
          const float4 z4 = *(const float4*)(zb + nk * ZSTR + dd);
          x.x += wk[k] * z4.x; x.y += wk[k] * z4.y;
          x.z += wk[k] * z4.z; x.w += wk[k] * z4.w;
        }
        xr[it] = x;
      }
      #pragma unroll
      for (int it = 0; it < NIT; ++it) {
        const int i = it * IPG + ioff;
        *(float4*)(zb + i * ZSTR + dd) = xr[it];
      }
    }
  }
  __syncthreads();

  // ======== PHASE D: h = x@W + b; LN; relu.  wave = node i; lane group owns (o-range, b-subset)
  {
    constexpr int GS  = O / 4;     // lanes per output group
    constexpr int NG  = 64 / GS;   // groups per wave
    constexpr int NBL = 8 / NG;    // batch elems per lane
    const int i   = wave;
    const int grp = u / GS;
    const int lo  = u - grp * GS;
    const int o   = lo * 4;
    const int b0  = grp * NBL;

    float4 acc4[NBL];
    {
      const float4 bias4 = *(const float4*)(bias + i * O + o);
      #pragma unroll
      for (int j = 0; j < NBL; ++j) acc4[j] = bias4;
    }
    const float* wrow = W + (size_t)i * D * O + o;
    if constexpr (D == 3) {
      #pragma unroll
      for (int d = 0; d < 3; ++d) {
        const float4 w4 = *(const float4*)(wrow + d * O);
        #pragma unroll
        for (int j = 0; j < NBL; ++j) {
          const float xs = zAll[(b0 + j) * SLICE + i * ZSTR + d];  // wave-uniform -> LDS broadcast
          acc4[j].x += xs * w4.x; acc4[j].y += xs * w4.y;
          acc4[j].z += xs * w4.z; acc4[j].w += xs * w4.w;
        }
      }
    } else {
      #pragma unroll 2
      for (int d = 0; d < D; d += 4) {
        const float4 w0 = *(const float4*)(wrow + (d + 0) * O);
        const float4 w1 = *(const float4*)(wrow + (d + 1) * O);
        const float4 w2 = *(const float4*)(wrow + (d + 2) * O);
        const float4 w3 = *(const float4*)(wrow + (d + 3) * O);
        #pragma unroll
        for (int j = 0; j < NBL; ++j) {
          const float4 x4 = *(const float4*)(zAll + (b0 + j) * SLICE + i * ZSTR + d);
          acc4[j].x += x4.x * w0.x + x4.y * w1.x + x4.z * w2.x + x4.w * w3.x;
          acc4[j].y += x4.x * w0.y + x4.y * w1.y + x4.z * w2.y + x4.w * w3.y;
          acc4[j].z += x4.x * w0.z + x4.y * w1.z + x4.z * w2.z + x4.w * w3.z;
          acc4[j].w += x4.x * w0.w + x4.y * w1.w + x4.z * w2.w + x4.w * w3.w;
        }
      }
    }
    // LayerNorm per (b, node i) across O outputs spread over GS lanes
    const float4 gg = *(const float4*)(gsc + i * O + o);
    const float4 bb = *(const float4*)(bsh + i * O + o);
    #pragma unroll
    for (int j = 0; j < NBL; ++j) {
      float4 a4 = acc4[j];
      float s1 = a4.x + a4.y + a4.z + a4.w;
      float s2 = a4.x * a4.x + a4.y * a4.y + a4.z * a4.z + a4.w * a4.w;
      #pragma unroll
      for (int mk = GS >> 1; mk; mk >>= 1) {
        s1 += __shfl_xor(s1, mk, GS);
        s2 += __shfl_xor(s2, mk, GS);
      }
      const float mean = s1 * (1.0f / O);
      const float var  = s2 * (1.0f / O) - mean * mean;
      const float rs   = rsqrtf(var + EPSLN);
      float4 r;
      r.x = fmaxf((a4.x - mean) * rs * gg.x + bb.x, 0.f);
      r.y = fmaxf((a4.y - mean) * rs * gg.y + bb.y, 0.f);
      r.z = fmaxf((a4.z - mean) * rs * gg.z + bb.z, 0.f);
      r.w = fmaxf((a4.w - mean) * rs * gg.w + bb.w, 0.f);
      *(float4*)(zAll + (b0 + j) * SLICE + i * ZSTR + o) = r;
    }
  }
  __syncthreads();
}

__launch_bounds__(512, 4)
__global__ void actor_fused(KP p)
{
  __shared__ float zA[NWAVE * SLICE];
  __shared__ float wbuf[NWAVE * WSTR];
  __shared__ float gbuf[NWAVE * WSTR];
  const int wave = threadIdx.x >> 6;
  const int u = threadIdx.x & 63;
  const int bbase = blockIdx.x * NWAVE;

  // ---- init: wave = batch element
  {
    const int gb = bbase + wave;
    // gates: gbuf[b][i*8+k] = A[b, gidx(i,k)]
    const int i = u >> 3, o8 = u & 7;
    if (o8 < 7) {
      const int j = o8 + (o8 >= i);
      const int gidx = (i == 0 && j <= 3) ? j : 8 * j + i;
      gbuf[wave * WSTR + i * 8 + o8] = p.A[gb * 64 + gidx];
    }
    if (u < 24) {
      const int ii = u / 3, dd = u - ii * 3;
      zA[wave * SLICE + ii * ZSTR + dd] = p.Z[ii][gb * 3 + dd];
    }
  }
  __syncthreads();

  layer_fwd<3, 256>(zA, wbuf, gbuf, wave, u, p.W0, p.b0, p.g0, p.be0, p.Wg0, p.bg0, nullptr, false);
  layer_fwd<256, 128>(zA, wbuf, gbuf, wave, u, p.W1, p.b1, p.g1, p.be1, p.Wg1, p.bg1, p.WgT1, p.useT != 0);
  layer_fwd<128, 64>(zA, wbuf, gbuf, wave, u, p.W2, p.b2, p.g2, p.be2, p.Wg2, p.bg2, p.WgT2, p.useT != 0);

  // ---- output projection 64 -> 5, tanh.  wave = node i; lane = (b, o8<5)
  {
    const int i = wave;
    const int b = u >> 3, o8 = u & 7;
    if (o8 < 5) {
      float acc = p.bout[i * 5 + o8];
      const float* wp = p.Wout + i * 64 * 5 + o8;
      const float* zr = zA + b * SLICE + i * ZSTR;
      #pragma unroll 8
      for (int d = 0; d < 64; ++d) acc += zr[d] * wp[d * 5];
      p.out[((size_t)(bbase + b) * 8 + i) * 5 + o8] = tanhf(acc);
    }
  }
}

extern "C" void kernel_launch(void* const* d_in, const int* in_sizes, int n_in,
                              void* d_out, int out_size, void* d_ws, size_t ws_size,
                              hipStream_t stream) {
  KP p;
  for (int i = 0; i < 8; ++i) p.Z[i] = (const float*)d_in[1 + i];
  p.A   = (const float*)d_in[9];
  p.W0  = (const float*)d_in[10]; p.b0 = (const float*)d_in[11];
  p.g0  = (const float*)d_in[12]; p.be0 = (const float*)d_in[13];
  p.Wg0 = (const float*)d_in[14]; p.bg0 = (const float*)d_in[15];
  p.W1  = (const float*)d_in[16]; p.b1 = (const float*)d_in[17];
  p.g1  = (const float*)d_in[18]; p.be1 = (const float*)d_in[19];
  p.Wg1 = (const float*)d_in[20]; p.bg1 = (const float*)d_in[21];
  p.W2  = (const float*)d_in[22]; p.b2 = (const float*)d_in[23];
  p.g2  = (const float*)d_in[24]; p.be2 = (const float*)d_in[25];
  p.Wg2 = (const float*)d_in[26]; p.bg2 = (const float*)d_in[27];
  p.Wout = (const float*)d_in[28]; p.bout = (const float*)d_in[29];
  p.out = (float*)d_out;

  const size_t t1_elems = 8 * 1792 * 7;  // 100352
  const size_t t2_elems = 8 * 896 * 7;   // 50176
  float* wsf = (float*)d_ws;
  const bool useT = ws_size >= (t1_elems + t2_elems) * sizeof(float);
  p.WgT1 = wsf;
  p.WgT2 = wsf + t1_elems;
  p.useT = useT ? 1 : 0;

  if (useT) {
    hipLaunchKernelGGL(transpose_wg, dim3((unsigned)((t1_elems + 255) / 256)), dim3(256), 0, stream,
                       p.Wg1, wsf, 256);
    hipLaunchKernelGGL(transpose_wg, dim3((unsigned)((t2_elems + 255) / 256)), dim3(256), 0, stream,
                       p.Wg2, wsf + t1_elems, 128);
  }
  hipLaunchKernelGGL(actor_fused, dim3(8192 / NWAVE), dim3(512), 0, stream, p);
}

// Round 3
// 91.640 us; speedup vs baseline: 5.1558x; 3.2144x over previous
//
#include <hip/hip_runtime.h>
#include <math.h>

typedef _Float16 v8h __attribute__((ext_vector_type(8)));
typedef float    v4f __attribute__((ext_vector_type(4)));

#define DSTR  264      // zh row stride in halves (528B = 4 dwords mod 32 banks -> 2-way free)
#define WSTR  68       // wbuf/gbuf per-batch stride (floats)
#define EPSLN 1e-5f

struct KP {
  const float* Z[8];
  const float* A;
  const float *W0, *b0, *g0, *be0, *Wg0, *bg0;
  const float *b1, *g1, *be1, *bg1;
  const float *b2, *g2, *be2, *bg2;
  const float *bout;
  const _Float16 *WgT1, *WgT2, *WT1, *WT2, *WoT;
  float* out;
};

// dst[i][o][f] = (o<Osrc) ? src[i][f][o] : 0   (f16), t enumerates ((i*Opad+o)*F+f)
__global__ void cvt_w(const float* __restrict__ src, _Float16* __restrict__ dst,
                      int F, int Osrc, int Opad) {
  const int total = 8 * Opad * F;
  for (int t = blockIdx.x * 256 + threadIdx.x; t < total; t += gridDim.x * 256) {
    const int f  = t % F;
    const int io = t / F;
    const int o  = io % Opad;
    const int i  = io / Opad;
    dst[t] = (o < Osrc) ? (_Float16)src[(i * F + f) * Osrc + o] : (_Float16)0.f;
  }
}

// One MFMA layer: gate (K=7*D, N=7 padded 16) + softmax*gates -> wbuf;
// dense (M=32, N=O, K=D) with on-the-fly x = z_i + sum_k w_k z_nk; LN+relu; h -> zh.
template<int D, int O>
__device__ __forceinline__ void mfma_layer(
    _Float16* __restrict__ zh, float* __restrict__ wbuf, const float* __restrict__ gbuf,
    const _Float16* __restrict__ WgT, const float* __restrict__ bg,
    const _Float16* __restrict__ WT, const float* __restrict__ bias,
    const float* __restrict__ g, const float* __restrict__ be,
    int i, int q, int r)
{
  constexpr int KS = D / 32;   // k-steps per neighbor block (gate) / per dense K
  constexpr int NT = O / 16;   // dense n-tiles

  // ---------------- gate: logits[32b x 16(7)] = Zall @ WgT_i ----------------
  v4f gacc[2];
  #pragma unroll
  for (int mt = 0; mt < 2; ++mt) gacc[mt] = (v4f){0.f, 0.f, 0.f, 0.f};
  #pragma unroll
  for (int nb = 0; nb < 7; ++nb) {
    const int nk = nb + (nb >= i);
    for (int ks = 0; ks < KS; ++ks) {
      const int d0 = ks * 32 + q * 8;
      // B-frag: lane(q,r): WgT[i][o=r][k=nb*D+d0..+7]  (rows r>=8 alias next region: finite, cols discarded)
      const v8h bf = *(const v8h*)(WgT + (size_t)(i * 8 + r) * (7 * D) + nb * D + d0);
      #pragma unroll
      for (int mt = 0; mt < 2; ++mt) {
        const v8h af = *(const v8h*)(zh + ((nk * 32 + mt * 16 + r) * DSTR + d0));
        gacc[mt] = __builtin_amdgcn_mfma_f32_16x16x32_f16(af, bf, gacc[mt], 0, 0, 0);
      }
    }
  }
  // softmax over cols r<7 (within 16-lane groups), times input gates -> wbuf
  const float bgv = (r < 7) ? bg[i * 7 + r] : 0.f;
  #pragma unroll
  for (int mt = 0; mt < 2; ++mt) {
    #pragma unroll
    for (int reg = 0; reg < 4; ++reg) {
      const float v = gacc[mt][reg] + bgv;
      float m = (r < 7) ? v : -3.0e38f;
      #pragma unroll
      for (int mk = 1; mk < 16; mk <<= 1) m = fmaxf(m, __shfl_xor(m, mk, 16));
      const float e = (r < 7) ? __expf(v - m) : 0.f;
      float s = e;
      #pragma unroll
      for (int mk = 1; mk < 16; mk <<= 1) s += __shfl_xor(s, mk, 16);
      const int b = mt * 16 + q * 4 + reg;
      if (r < 7) wbuf[b * WSTR + i * 8 + r] = (e / s) * gbuf[b * WSTR + i * 8 + r];
    }
  }
  __syncthreads();

  // ---------------- dense: h = (z_i + sum_k w_k z_nk) @ W_i + b ----------------
  v4f acc[2][NT];
  #pragma unroll
  for (int mt = 0; mt < 2; ++mt)
    #pragma unroll
    for (int n = 0; n < NT; ++n) acc[mt][n] = (v4f){0.f, 0.f, 0.f, 0.f};

  _Float16 wh[2][7];
  #pragma unroll
  for (int mt = 0; mt < 2; ++mt)
    #pragma unroll
    for (int nb = 0; nb < 7; ++nb)
      wh[mt][nb] = (_Float16)wbuf[(mt * 16 + r) * WSTR + i * 8 + nb];

  #pragma unroll 2
  for (int ks = 0; ks < KS; ++ks) {
    const int d0 = ks * 32 + q * 8;
    v8h af[2];
    #pragma unroll
    for (int mt = 0; mt < 2; ++mt) {
      const int row = (i * 32 + mt * 16 + r) * DSTR + d0;
      v8h x = *(const v8h*)(zh + row);
      #pragma unroll
      for (int nb = 0; nb < 7; ++nb) {
        const int nk = nb + (nb >= i);
        const v8h zn = *(const v8h*)(zh + ((nk * 32 + mt * 16 + r) * DSTR + d0));
        x += zn * wh[mt][nb];
      }
      af[mt] = x;
    }
    #pragma unroll
    for (int n = 0; n < NT; ++n) {
      const v8h bf = *(const v8h*)(WT + (size_t)(i * O + n * 16 + r) * D + d0);
      acc[0][n] = __builtin_amdgcn_mfma_f32_16x16x32_f16(af[0], bf, acc[0][n], 0, 0, 0);
      acc[1][n] = __builtin_amdgcn_mfma_f32_16x16x32_f16(af[1], bf, acc[1][n], 0, 0, 0);
    }
  }

  // bias + LayerNorm + relu, all in regs (C/D: col=n*16+r, row=mt*16+q*4+reg)
  float bv[NT], gv[NT], bev[NT];
  #pragma unroll
  for (int n = 0; n < NT; ++n) {
    const int o = n * 16 + r;
    bv[n] = bias[i * O + o]; gv[n] = g[i * O + o]; bev[n] = be[i * O + o];
  }
  #pragma unroll
  for (int mt = 0; mt < 2; ++mt) {
    #pragma unroll
    for (int reg = 0; reg < 4; ++reg) {
      float s1 = 0.f, s2 = 0.f;
      #pragma unroll
      for (int n = 0; n < NT; ++n) {
        const float h = acc[mt][n][reg] + bv[n];
        acc[mt][n][reg] = h;
        s1 += h; s2 += h * h;
      }
      #pragma unroll
      for (int mk = 1; mk < 16; mk <<= 1) { s1 += __shfl_xor(s1, mk, 16); s2 += __shfl_xor(s2, mk, 16); }
      const float mean = s1 * (1.f / O);
      const float var  = s2 * (1.f / O) - mean * mean;
      const float rs   = rsqrtf(var + EPSLN);
      #pragma unroll
      for (int n = 0; n < NT; ++n) {
        const float h = (acc[mt][n][reg] - mean) * rs * gv[n] + bev[n];
        acc[mt][n][reg] = fmaxf(h, 0.f);
      }
    }
  }
  __syncthreads();   // all waves done reading zh (dense A-frags)
  #pragma unroll
  for (int mt = 0; mt < 2; ++mt)
    #pragma unroll
    for (int n = 0; n < NT; ++n)
      #pragma unroll
      for (int reg = 0; reg < 4; ++reg) {
        const int b = mt * 16 + q * 4 + reg;
        zh[(i * 32 + b) * DSTR + n * 16 + r] = (_Float16)acc[mt][n][reg];
      }
  __syncthreads();
}

__launch_bounds__(512, 2)
__global__ void actor_mfma(KP p)
{
  __shared__ __align__(16) _Float16 zh[8 * 32 * DSTR];   // [node][b][d]  135.2 KB
  __shared__ float wbuf[32 * WSTR];                      // [b][i*8+k]     8.7 KB
  __shared__ float gbuf[32 * WSTR];                      //                8.7 KB
  __shared__ float xbuf[8 * 32 * 4];                     // layer0 x       4.0 KB

  const int i = threadIdx.x >> 6;        // wave = node
  const int u = threadIdx.x & 63;
  const int q = u >> 4, r = u & 15;
  const int bbase = blockIdx.x * 32;

  // ---- init: Z (f16) + gates
  {
    #pragma unroll
    for (int c = 0; c < 2; ++c) {
      const int idx = c * 64 + u;
      if (idx < 96) {
        const int b = idx / 3, d = idx - 3 * (idx / 3);
        zh[(i * 32 + b) * DSTR + d] = (_Float16)p.Z[i][(size_t)(bbase + b) * 3 + d];
      }
    }
    for (int t = threadIdx.x; t < 32 * 64; t += 512) {
      const int b = t >> 6, ik = t & 63;
      const int ii = ik >> 3, k = ik & 7;
      if (k < 7) {
        const int j = k + (k >= ii);
        const int gidx = (ii == 0 && j <= 3) ? j : 8 * j + ii;
        gbuf[b * WSTR + ik] = p.A[(size_t)(bbase + b) * 64 + gidx];
      }
    }
  }
  __syncthreads();

  // ================= layer 0 (VALU, tiny K) =================
  // gate0
  for (int c = 0; c < 4; ++c) {
    const int b = c * 8 + (u >> 3), o8 = u & 7;
    float v = -3.0e38f;
    if (o8 < 7) {
      v = p.bg0[i * 7 + o8];
      #pragma unroll
      for (int k = 0; k < 7; ++k) {
        const int nk = k + (k >= i);
        const _Float16* zp = zh + (nk * 32 + b) * DSTR;
        const float* wp = p.Wg0 + (i * 21 + k * 3) * 7 + o8;
        v += (float)zp[0] * wp[0] + (float)zp[1] * wp[7] + (float)zp[2] * wp[14];
      }
    }
    float m = v;
    #pragma unroll
    for (int mk = 1; mk < 8; mk <<= 1) m = fmaxf(m, __shfl_xor(m, mk, 8));
    const float e = (o8 < 7) ? __expf(v - m) : 0.f;
    float s = e;
    #pragma unroll
    for (int mk = 1; mk < 8; mk <<= 1) s += __shfl_xor(s, mk, 8);
    if (o8 < 7) wbuf[b * WSTR + i * 8 + o8] = (e / s) * gbuf[b * WSTR + i * 8 + o8];
  }
  __syncthreads();
  // NZ0 -> xbuf
  #pragma unroll
  for (int c = 0; c < 2; ++c) {
    const int idx = c * 64 + u;
    if (idx < 96) {
      const int b = idx / 3, d = idx - 3 * (idx / 3);
      float x = (float)zh[(i * 32 + b) * DSTR + d];
      #pragma unroll
      for (int k = 0; k < 7; ++k) {
        const int nk = k + (k >= i);
        x += wbuf[b * WSTR + i * 8 + k] * (float)zh[(nk * 32 + b) * DSTR + d];
      }
      xbuf[(i * 32 + b) * 4 + d] = x;
    }
  }
  __syncthreads();
  // dense0: O=256, K=3 ; writes zh[i][b][0..255]
  {
    const int bh = u >> 5, lo = u & 31, o = lo * 8;
    float w0r[3][8], b0r[8], g0r[8], be0r[8];
    #pragma unroll
    for (int d = 0; d < 3; ++d)
      #pragma unroll
      for (int j = 0; j < 8; ++j) w0r[d][j] = p.W0[(i * 3 + d) * 256 + o + j];
    #pragma unroll
    for (int j = 0; j < 8; ++j) {
      b0r[j] = p.b0[i * 256 + o + j];
      g0r[j] = p.g0[i * 256 + o + j];
      be0r[j] = p.be0[i * 256 + o + j];
    }
    for (int it = 0; it < 16; ++it) {
      const int b = it * 2 + bh;
      const float x0 = xbuf[(i * 32 + b) * 4 + 0];
      const float x1 = xbuf[(i * 32 + b) * 4 + 1];
      const float x2 = xbuf[(i * 32 + b) * 4 + 2];
      float h[8], s1 = 0.f, s2 = 0.f;
      #pragma unroll
      for (int j = 0; j < 8; ++j) {
        const float v = b0r[j] + x0 * w0r[0][j] + x1 * w0r[1][j] + x2 * w0r[2][j];
        h[j] = v; s1 += v; s2 += v * v;
      }
      #pragma unroll
      for (int mk = 1; mk < 32; mk <<= 1) { s1 += __shfl_xor(s1, mk, 32); s2 += __shfl_xor(s2, mk, 32); }
      const float mean = s1 * (1.f / 256.f);
      const float var  = s2 * (1.f / 256.f) - mean * mean;
      const float rs   = rsqrtf(var + EPSLN);
      v8h hv;
      #pragma unroll
      for (int j = 0; j < 8; ++j)
        hv[j] = (_Float16)fmaxf((h[j] - mean) * rs * g0r[j] + be0r[j], 0.f);
      *(v8h*)(zh + (i * 32 + b) * DSTR + o) = hv;
    }
  }
  __syncthreads();

  // ================= layers 1,2 (MFMA) =================
  mfma_layer<256, 128>(zh, wbuf, gbuf, p.WgT1, p.bg1, p.WT1, p.b1, p.g1, p.be1, i, q, r);
  mfma_layer<128, 64 >(zh, wbuf, gbuf, p.WgT2, p.bg2, p.WT2, p.b2, p.g2, p.be2, i, q, r);

  // ================= output 64 -> 5, tanh (VALU) =================
  {
    const int b8 = u >> 3, o8 = u & 7;
    v8h wreg[8];
    #pragma unroll
    for (int t8 = 0; t8 < 8; ++t8)
      wreg[t8] = *(const v8h*)(p.WoT + (i * 8 + o8) * 64 + t8 * 8);
    const float bo = (o8 < 5) ? p.bout[i * 5 + o8] : 0.f;
    for (int c = 0; c < 4; ++c) {
      const int b = c * 8 + b8;
      const _Float16* zp = zh + (i * 32 + b) * DSTR;
      float acc = bo;
      #pragma unroll
      for (int t8 = 0; t8 < 8; ++t8) {
        const v8h z8 = *(const v8h*)(zp + t8 * 8);
        #pragma unroll
        for (int j = 0; j < 8; ++j) acc += (float)z8[j] * (float)wreg[t8][j];
      }
      if (o8 < 5)
        p.out[((size_t)(bbase + b) * 8 + i) * 5 + o8] = tanhf(acc);
    }
  }
}

extern "C" void kernel_launch(void* const* d_in, const int* in_sizes, int n_in,
                              void* d_out, int out_size, void* d_ws, size_t ws_size,
                              hipStream_t stream) {
  KP p;
  for (int i = 0; i < 8; ++i) p.Z[i] = (const float*)d_in[1 + i];
  p.A   = (const float*)d_in[9];
  p.W0  = (const float*)d_in[10]; p.b0 = (const float*)d_in[11];
  p.g0  = (const float*)d_in[12]; p.be0 = (const float*)d_in[13];
  p.Wg0 = (const float*)d_in[14]; p.bg0 = (const float*)d_in[15];
  const float* W1  = (const float*)d_in[16]; p.b1 = (const float*)d_in[17];
  p.g1  = (const float*)d_in[18]; p.be1 = (const float*)d_in[19];
  const float* Wg1 = (const float*)d_in[20]; p.bg1 = (const float*)d_in[21];
  const float* W2  = (const float*)d_in[22]; p.b2 = (const float*)d_in[23];
  p.g2  = (const float*)d_in[24]; p.be2 = (const float*)d_in[25];
  const float* Wg2 = (const float*)d_in[26]; p.bg2 = (const float*)d_in[27];
  const float* Wout = (const float*)d_in[28]; p.bout = (const float*)d_in[29];
  p.out = (float*)d_out;

  // f16 transposed weights in ws (half offsets)
  _Float16* wsH = (_Float16*)d_ws;
  _Float16* WgT1 = wsH;                 // 8*8*1792 = 114688
  _Float16* WgT2 = wsH + 114688;        // 8*8*896  =  57344
  _Float16* WoT  = wsH + 172032;        // 8*8*64   =   4096
  _Float16* WT1  = wsH + 176128;        // 8*128*256= 262144
  _Float16* WT2  = wsH + 438272;        // 8*64*128 =  65536  -> total 503808 halves (~0.96MB)
  p.WgT1 = WgT1; p.WgT2 = WgT2; p.WoT = WoT; p.WT1 = WT1; p.WT2 = WT2;

  hipLaunchKernelGGL(cvt_w, dim3(256), dim3(256), 0, stream, Wg1,  WgT1, 1792, 7,   8);
  hipLaunchKernelGGL(cvt_w, dim3(128), dim3(256), 0, stream, Wg2,  WgT2, 896,  7,   8);
  hipLaunchKernelGGL(cvt_w, dim3(16),  dim3(256), 0, stream, Wout, WoT,  64,   5,   8);
  hipLaunchKernelGGL(cvt_w, dim3(512), dim3(256), 0, stream, W1,   WT1,  256,  128, 128);
  hipLaunchKernelGGL(cvt_w, dim3(128), dim3(256), 0, stream, W2,   WT2,  128,  64,  64);

  hipLaunchKernelGGL(actor_mfma, dim3(256), dim3(512), 0, stream, p);
}